// Round 5
// baseline (1414.027 us; speedup 1.0000x reference)
//
#include <hip/hip_runtime.h>
#include <hip/hip_bf16.h>

// Problem constants
#define S_LEN 8192
#define NH    16
#define HD    128      // head dim
#define HID   2048     // hidden
#define NQKV  6144     // fused QKV output width
#define CHUNK 12
#define MP    12
#define CTX   24
#define POS   13
#define NBLK  683      // ceil(8192/12)

typedef short bf16x8 __attribute__((ext_vector_type(8)));
typedef float f32x4  __attribute__((ext_vector_type(4)));
typedef unsigned short u16;
typedef u16 u16x8 __attribute__((ext_vector_type(8)));
typedef u16 u16x4 __attribute__((ext_vector_type(4)));

#define MFMA16 __builtin_amdgcn_mfma_f32_16x16x32_bf16

__device__ __forceinline__ void glds16(const u16* g, u16* l) {
  __builtin_amdgcn_global_load_lds(
      (__attribute__((address_space(1))) void*)(void*)g,
      (__attribute__((address_space(3))) void*)l, 16, 0, 0);
}

__device__ __forceinline__ u16 f2b(float f) {
  __hip_bfloat16 h = __float2bfloat16(f);
  return *(u16*)&h;
}

// ---------------------------------------------------------------- convert
__global__ __launch_bounds__(256) void f32_to_bf16(const float* __restrict__ in,
                                                   u16* __restrict__ out, int n) {
  int i = (blockIdx.x * 256 + threadIdx.x) * 4;
  if (i < n) {
    float4 v = *(const float4*)(in + i);
    u16x4 o = {f2b(v.x), f2b(v.y), f2b(v.z), f2b(v.w)};
    *(u16x4*)(out + i) = o;
  }
}

// ---------------------------------------------------------------- transpose x4
__global__ __launch_bounds__(256) void transpose4(const float* __restrict__ W0,
                                                  const float* __restrict__ W1,
                                                  const float* __restrict__ W2,
                                                  const float* __restrict__ W3,
                                                  u16* __restrict__ out) {
  __shared__ u16 t[64][72];
  const int z = blockIdx.z;
  const float* in = (z == 0) ? W0 : (z == 1) ? W1 : (z == 2) ? W2 : W3;
  u16* dst = out + (size_t)z * HID * HID;
  const int bx = blockIdx.x * 64, by = blockIdx.y * 64;
  const int x = threadIdx.x & 63;
  const int y4 = threadIdx.x >> 6;
  for (int r = y4; r < 64; r += 4)
    t[r][x] = f2b(in[(size_t)(by + r) * HID + bx + x]);
  __syncthreads();
  for (int r = y4; r < 64; r += 4)
    dst[(size_t)(bx + r) * HID + by + x] = t[x][r];
}

// ---------------------------------------------------------------- q scale
__global__ void qscale_kernel(const float* __restrict__ pds, float* __restrict__ qs) {
  int d = threadIdx.x;
  float x = pds[d];
  float sp = log1pf(expf(x));
  qs[d] = 0.08838834764831845f * 1.4426950408889634f * sp;
}

// ---------------------------------------------------------------- rel_k
__global__ __launch_bounds__(256) void relk_atomic(const float* __restrict__ pos,
                                                   const float* __restrict__ Wrel,
                                                   float* __restrict__ RELF) {
  const int col = blockIdx.x * 256 + threadIdx.x;
  const int c0 = blockIdx.y * 256;
  float acc[POS] = {};
  for (int c = c0; c < c0 + 256; ++c) {
    float wv = Wrel[(size_t)c * HID + col];
#pragma unroll
    for (int p = 0; p < POS; ++p) acc[p] += pos[p * HID + c] * wv;
  }
#pragma unroll
  for (int p = 0; p < POS; ++p) atomicAdd(&RELF[p * HID + col], acc[p]);
}

__global__ __launch_bounds__(256) void relk_cvt(const float* __restrict__ RELF,
                                                u16* __restrict__ REL) {
  int i = blockIdx.x * 256 + threadIdx.x;
  if (i < POS * HID) REL[i] = f2b(RELF[i]);
}

// ---------------------------------------------------------------- GEMM
// 256xBN tile, BK=32, ring-2 LDS, 4 waves (2m x 2n), wave-tile 128x(BN/2).
// KEY CHANGE vs r4: 64 KB LDS (BN=256) -> TWO independent blocks per CU.
// The co-resident block's waves fill the MFMA pipe while this block drains
// lgkm/vmcnt/barrier (m114 cross-wave overlap) -- removes the barrier
// lockstep that serialized LDS-pipe and MFMA-pipe (r4: 2554 cyc/tile =
// 1242 MFMA + 1152 LDS, serial). Wave-tile 128x128 also cuts LDS reads to
// 16 per 64 MFMA (0.25/MFMA vs 0.375) -> LDS demand ~0.62 of MFMA time.
//
// Schedule per tile t: stage(t+1) into buf (t+1)&1 -> ds_read 16 frags from
// buf t&1 -> lgkmcnt(0) -> 64 MFMA -> vmcnt(0) -> s_barrier.
// Hazards: reads of buf (t+1)&1 finished before end-of-(t-1) barrier (lgkm0
// precedes each wave's barrier arrival) -> stage(t+1) WAR-safe; vmcnt(0)
// waits only the 8 stage loads (issued ~1 tile earlier). Exposed drains are
// covered by the other block on the CU.
//
// LDS layout (0-conflict, verified r3/r4): logical [256 r][32 k] -> physical
// [128 prow][8 slot]: prow=r>>1, sl=(r&1)*4+(k>>3), phys p = sl ^ (prow&7).
// Stage keeps LDS dest LINEAR (global_load_lds) and applies the same
// involution to the GLOBAL source address (both-sides-or-neither).
#define BMT 256
#define BKT 32
#define NT  (HID / BKT)   // 64

template <int BN>
__global__ __launch_bounds__(256, 2) void gemm_bt(const u16* __restrict__ A,
                                                  const u16* __restrict__ Bt,
                                                  u16* __restrict__ Co,
                                                  float* __restrict__ Cf,
                                                  const float* __restrict__ colscale,
                                                  int NN, int csLimit) {
  constexpr int NJ = BN / 32;          // B frags per wave (8 or 4)
  constexpr int BROWS = BN / 4;        // B rows staged per wave (64 or 32)
  constexpr int BCALLS = BROWS / 16;   // glds calls for B (4 or 2)
  __shared__ u16 lds[2][(256 + BN) * 32];  // A at 0, B at 8192 (u16 units)

  const int tid = threadIdx.x;
  const int lane = tid & 63, w = tid >> 6;   // 4 waves
  const int quad = lane >> 4, l = lane & 15;
  const int wm = (w >> 1) * 128;
  const int wn = (w & 1) * (BN / 2);

  // XCD mapping: per XCD 4 bm-panels (A L2-friendly), bn streams.
  const int orig = blockIdx.y * gridDim.x + blockIdx.x;
  const int xcd = orig & 7, k = orig >> 3;
  const int bm = (xcd * 4 + (k & 3)) * BMT;
  const int bn = (k >> 2) * BN;

  // Read-side swizzle constant (rows are 16-aligned + l).
  const int rdoff = (l >> 1) * 64 + (((((l & 1) << 2) | quad)) ^ ((l >> 1) & 7)) * 8;

  // Stage side: lane's phys slot lane&7 at prow base+lane>>3; fetch logical
  // chunk sl = (lane&7)^(lane>>3): global row 2*(lane>>3)+(sl>>2), k-chunk sl&3.
  const int sl = (lane & 7) ^ (lane >> 3);
  const int srow = ((lane >> 3) << 1) + (sl >> 2);
  const int sk = (sl & 3) * 8;
  const u16* Ag = A + (size_t)(bm + w * 64 + srow) * HID + sk;
  const u16* Bg = Bt + (size_t)(bn + w * BROWS + srow) * HID + sk;

  f32x4 acc[8][NJ] = {};

  auto STAGE = [&](int buf, int t) {
    const int kt = t * BKT;
    u16* dA = &lds[buf][w * 2048];
#pragma unroll
    for (int c = 0; c < 4; ++c)
      glds16(Ag + (size_t)c * 16 * HID + kt, dA + c * 512);
    u16* dB = &lds[buf][8192 + w * (BROWS * 32)];
#pragma unroll
    for (int c = 0; c < BCALLS; ++c)
      glds16(Bg + (size_t)c * 16 * HID + kt, dB + c * 512);
  };

  STAGE(0, 0);
  asm volatile("s_waitcnt vmcnt(0)" ::: "memory");
  __builtin_amdgcn_s_barrier();

#pragma unroll 1
  for (int t = 0; t < NT; ++t) {
    const int cur = t & 1;
    if (t + 1 < NT) STAGE(cur ^ 1, t + 1);

    const u16* bufA = &lds[cur][0];
    const u16* bufB = &lds[cur][8192];
    bf16x8 af[8], bfr[NJ];
#pragma unroll
    for (int i = 0; i < 8; ++i)
      af[i] = *(const bf16x8*)(bufA + (wm + i * 16) * 32 + rdoff);
#pragma unroll
    for (int j = 0; j < NJ; ++j)
      bfr[j] = *(const bf16x8*)(bufB + (wn + j * 16) * 32 + rdoff);
    asm volatile("s_waitcnt lgkmcnt(0)" ::: "memory");
    __builtin_amdgcn_sched_barrier(0);

    __builtin_amdgcn_s_setprio(1);
#pragma unroll
    for (int i = 0; i < 8; ++i)
#pragma unroll
      for (int j = 0; j < NJ; ++j)
        acc[i][j] = MFMA16(af[i], bfr[j], acc[i][j], 0, 0, 0);
    __builtin_amdgcn_s_setprio(0);

    if (t + 1 < NT) {
      asm volatile("s_waitcnt vmcnt(0)" ::: "memory");
      __builtin_amdgcn_sched_barrier(0);
      __builtin_amdgcn_s_barrier();
    }
  }

  // epilogue
#pragma unroll
  for (int i = 0; i < 8; ++i)
#pragma unroll
    for (int j = 0; j < NJ; ++j)
#pragma unroll
      for (int r = 0; r < 4; ++r) {
        int row = bm + wm + i * 16 + quad * 4 + r;
        int col = bn + wn + j * 16 + l;
        float v = acc[i][j][r];
        if (colscale && col < csLimit) v *= colscale[col & (HD - 1)];
        if (Cf) Cf[(size_t)row * NN + col] = v;
        else    Co[(size_t)row * NN + col] = f2b(v);
      }
}

// ---------------------------------------------------------------- attention
__global__ __launch_bounds__(64) void attn_kernel(const u16* __restrict__ qkv,
                                                  const u16* __restrict__ relg,
                                                  u16* __restrict__ og) {
  __shared__ char smem[13824];
  u16* qs = (u16*)smem;            // [16][136] phase1 (4352 B)
  u16* ks = (u16*)(smem + 4352);   // [32][136] phase1 (8704 B)
  u16* vt = (u16*)smem;            // [128][48] phase2 (12288 B)
  u16* ps = (u16*)(smem + 12288);  // [16][48]  phase2 (1536 B)
  const int n = blockIdx.x, h = blockIdx.y;
  const int lane = threadIdx.x;
  const int quad = lane >> 4, l = lane & 15;
  const int base = n * CHUNK;
  const u16x8 zero8 = {0, 0, 0, 0, 0, 0, 0, 0};

  const u16* qg = qkv + h * HD;
  const u16* kg = qkv + 2048 + h * HD;
  const u16* vg = qkv + 4096 + h * HD;

  u16x8 vld[8];
#pragma unroll
  for (int i = 0; i < 8; ++i) {
    int id = lane + 64 * i;
    int ctx = id & 31, dc = id >> 5;
    int s = base + ctx - MP;
    vld[i] = (ctx < CTX && s >= 0 && s < S_LEN)
                 ? *(const u16x8*)(vg + (size_t)s * NQKV + dc * 8)
                 : zero8;
  }

#pragma unroll
  for (int i = 0; i < 4; ++i) {
    int id = lane + 64 * i;
    int c = id >> 4, dc = id & 15;
    int s = base + c;
    u16x8 v = (c < CHUNK && s < S_LEN)
                  ? *(const u16x8*)(qg + (size_t)s * NQKV + dc * 8)
                  : zero8;
    *(u16x8*)(qs + c * 136 + dc * 8) = v;
  }
#pragma unroll
  for (int i = 0; i < 8; ++i) {
    int id = lane + 64 * i;
    int ctx = id >> 4, dc = id & 15;
    int s = base + ctx - MP;
    u16x8 v = (ctx < CTX && s >= 0 && s < S_LEN)
                  ? *(const u16x8*)(kg + (size_t)s * NQKV + dc * 8)
                  : zero8;
    *(u16x8*)(ks + ctx * 136 + dc * 8) = v;
  }
  __syncthreads();

  f32x4 ac0 = {0, 0, 0, 0}, ac1 = {0, 0, 0, 0}, bd = {0, 0, 0, 0};
#pragma unroll
  for (int t = 0; t < 4; ++t) {
    int d0 = t * 32;
    bf16x8 aQ = *(const bf16x8*)(qs + l * 136 + d0 + quad * 8);
    bf16x8 bK0 = *(const bf16x8*)(ks + l * 136 + d0 + quad * 8);
    bf16x8 bK1 = *(const bf16x8*)(ks + (16 + l) * 136 + d0 + quad * 8);
    bf16x8 bR = {0, 0, 0, 0, 0, 0, 0, 0};
    if (l < POS)
      bR = *(const bf16x8*)(relg + (size_t)l * HID + h * HD + d0 + quad * 8);
    ac0 = MFMA16(aQ, bK0, ac0, 0, 0, 0);
    ac1 = MFMA16(aQ, bK1, ac1, 0, 0, 0);
    bd = MFMA16(aQ, bR, bd, 0, 0, 0);
  }

  float p0[4], p1[4];
#pragma unroll
  for (int r = 0; r < 4; ++r) {
    int c = quad * 4 + r;
    int pi0 = l - c;
    int pi1 = 16 + l - c;
    int sp0 = pi0 < 0 ? 0 : (pi0 > 15 ? 15 : pi0);
    int sp1 = pi1 < 0 ? 0 : (pi1 > 15 ? 15 : pi1);
    float b0 = __shfl(bd[r], quad * 16 + sp0, 64);
    float b1 = __shfl(bd[r], quad * 16 + sp1, 64);
    b0 = (pi0 >= 0 && pi0 < POS) ? b0 : 0.0f;
    b1 = (pi1 >= 0 && pi1 < POS) ? b1 : 0.0f;
    float s0 = tanhf((ac0[r] + b0) * (1.0f / 50.0f)) * 50.0f;
    float s1 = tanhf((ac1[r] + b1) * (1.0f / 50.0f)) * 50.0f;
    bool v1 = (l < (CTX - 16));
    if (!v1) s1 = -1e30f;
    float mx = fmaxf(s0, s1);
#pragma unroll
    for (int d = 1; d < 16; d <<= 1) mx = fmaxf(mx, __shfl_xor(mx, d, 64));
    float e0 = __expf(s0 - mx);
    float e1 = v1 ? __expf(s1 - mx) : 0.0f;
    float sm = e0 + e1;
#pragma unroll
    for (int d = 1; d < 16; d <<= 1) sm += __shfl_xor(sm, d, 64);
    float inv = 1.0f / sm;
    p0[r] = e0 * inv;
    p1[r] = e1 * inv;
  }
  __syncthreads();

#pragma unroll
  for (int i = 0; i < 8; ++i) {
    int id = lane + 64 * i;
    int ctx = id & 31, dc = id >> 5;
#pragma unroll
    for (int jj = 0; jj < 8; ++jj) vt[(dc * 8 + jj) * 48 + ctx] = vld[i][jj];
  }
#pragma unroll
  for (int r = 0; r < 4; ++r) {
    int c = quad * 4 + r;
    ps[c * 48 + l] = f2b(p0[r]);
    ps[c * 48 + 16 + l] = f2b(p1[r]);
  }
  __syncthreads();

  bf16x8 aP = *(const bf16x8*)(ps + l * 48 + quad * 8);
#pragma unroll
  for (int nt = 0; nt < 8; ++nt) {
    bf16x8 bV = *(const bf16x8*)(vt + (nt * 16 + l) * 48 + quad * 8);
    f32x4 o = {0, 0, 0, 0};
    o = MFMA16(aP, bV, o, 0, 0, 0);
#pragma unroll
    for (int r = 0; r < 4; ++r) {
      int c = quad * 4 + r;
      int s = base + c;
      if (c < CHUNK && s < S_LEN)
        og[(size_t)s * HID + h * HD + nt * 16 + l] = f2b(o[r]);
    }
  }
}

// ---------------------------------------------------------------- launch
extern "C" void kernel_launch(void* const* d_in, const int* in_sizes, int n_in,
                              void* d_out, int out_size, void* d_ws, size_t ws_size,
                              hipStream_t stream) {
  const float* x = (const float*)d_in[0];
  const float* pos = (const float*)d_in[1];
  const float* Wq = (const float*)d_in[2];
  const float* Wk = (const float*)d_in[3];
  const float* Wv = (const float*)d_in[4];
  const float* Wrel = (const float*)d_in[5];
  const float* Wpost = (const float*)d_in[6];
  const float* pds = (const float*)d_in[7];

  char* ws = (char*)d_ws;
  u16* WT  = (u16*)(ws);                      // 4 x [2048][2048] bf16 = 32 MB
  u16* xb  = (u16*)(ws + 33554432);           // [8192][2048] bf16 = 32 MB
  u16* AO  = xb;                              // alias: xb dead after QKV GEMM
  u16* QKV = (u16*)(ws + 67108864);           // [8192][6144] bf16 = 96 MB
  float* RELF = (float*)(ws + 167772160);     // [13][2048] f32
  u16* REL = (u16*)(ws + 167878656);          // [13][2048] bf16
  float* QS = (float*)(ws + 167931904);       // [128] f32

  const int NX = S_LEN * HID;
  f32_to_bf16<<<NX / 4 / 256, 256, 0, stream>>>(x, xb, NX);

  transpose4<<<dim3(32, 32, 4), 256, 0, stream>>>(Wq, Wk, Wv, Wpost, WT);
  qscale_kernel<<<1, 128, 0, stream>>>(pds, QS);

  hipMemsetAsync(RELF, 0, POS * HID * sizeof(float), stream);
  relk_atomic<<<dim3(8, 8), 256, 0, stream>>>(pos, Wrel, RELF);
  relk_cvt<<<(POS * HID + 255) / 256, 256, 0, stream>>>(RELF, REL);

  // fused QKV GEMM: Bt rows 0..6143 of WT; colscale on Q columns only
  gemm_bt<256><<<dim3(32, 24), 256, 0, stream>>>(xb, WT, QKV, nullptr, QS, NQKV, 2048);

  attn_kernel<<<dim3(NBLK, NH), 64, 0, stream>>>(QKV, REL, AO);

  // post GEMM: Bt = transposed Wpost (slab 3), f32 out; BN=128 -> 512 blocks
  gemm_bt<128><<<dim3(32, 16), 256, 0, stream>>>(AO, WT + (size_t)3 * HID * HID,
                                                 nullptr, (float*)d_out, nullptr, HID, 0);
}

// Round 6
// 555.955 us; speedup vs baseline: 2.5434x; 2.5434x over previous
//
#include <hip/hip_runtime.h>
#include <hip/hip_bf16.h>

// Problem constants
#define S_LEN 8192
#define NH    16
#define HD    128      // head dim
#define HID   2048     // hidden
#define NQKV  6144     // fused QKV output width
#define CHUNK 12
#define MP    12
#define CTX   24
#define POS   13
#define NBLK  683      // ceil(8192/12)

typedef short bf16x8 __attribute__((ext_vector_type(8)));
typedef float f32x4  __attribute__((ext_vector_type(4)));
typedef unsigned short u16;
typedef u16 u16x8 __attribute__((ext_vector_type(8)));
typedef u16 u16x4 __attribute__((ext_vector_type(4)));

#define MFMA16 __builtin_amdgcn_mfma_f32_16x16x32_bf16

__device__ __forceinline__ void glds16(const u16* g, u16* l) {
  __builtin_amdgcn_global_load_lds(
      (__attribute__((address_space(1))) void*)(void*)g,
      (__attribute__((address_space(3))) void*)l, 16, 0, 0);
}

__device__ __forceinline__ u16 f2b(float f) {
  __hip_bfloat16 h = __float2bfloat16(f);
  return *(u16*)&h;
}

// ---------------------------------------------------------------- convert
__global__ __launch_bounds__(256) void f32_to_bf16(const float* __restrict__ in,
                                                   u16* __restrict__ out, int n) {
  int i = (blockIdx.x * 256 + threadIdx.x) * 4;
  if (i < n) {
    float4 v = *(const float4*)(in + i);
    u16x4 o = {f2b(v.x), f2b(v.y), f2b(v.z), f2b(v.w)};
    *(u16x4*)(out + i) = o;
  }
}

// ---------------------------------------------------------------- transpose x4
__global__ __launch_bounds__(256) void transpose4(const float* __restrict__ W0,
                                                  const float* __restrict__ W1,
                                                  const float* __restrict__ W2,
                                                  const float* __restrict__ W3,
                                                  u16* __restrict__ out) {
  __shared__ u16 t[64][72];
  const int z = blockIdx.z;
  const float* in = (z == 0) ? W0 : (z == 1) ? W1 : (z == 2) ? W2 : W3;
  u16* dst = out + (size_t)z * HID * HID;
  const int bx = blockIdx.x * 64, by = blockIdx.y * 64;
  const int x = threadIdx.x & 63;
  const int y4 = threadIdx.x >> 6;
  for (int r = y4; r < 64; r += 4)
    t[r][x] = f2b(in[(size_t)(by + r) * HID + bx + x]);
  __syncthreads();
  for (int r = y4; r < 64; r += 4)
    dst[(size_t)(bx + r) * HID + by + x] = t[x][r];
}

// ---------------------------------------------------------------- q scale
__global__ void qscale_kernel(const float* __restrict__ pds, float* __restrict__ qs) {
  int d = threadIdx.x;
  float x = pds[d];
  float sp = log1pf(expf(x));
  qs[d] = 0.08838834764831845f * 1.4426950408889634f * sp;
}

// ---------------------------------------------------------------- rel_k
__global__ __launch_bounds__(256) void relk_atomic(const float* __restrict__ pos,
                                                   const float* __restrict__ Wrel,
                                                   float* __restrict__ RELF) {
  const int col = blockIdx.x * 256 + threadIdx.x;
  const int c0 = blockIdx.y * 256;
  float acc[POS] = {};
  for (int c = c0; c < c0 + 256; ++c) {
    float wv = Wrel[(size_t)c * HID + col];
#pragma unroll
    for (int p = 0; p < POS; ++p) acc[p] += pos[p * HID + c] * wv;
  }
#pragma unroll
  for (int p = 0; p < POS; ++p) atomicAdd(&RELF[p * HID + col], acc[p]);
}

__global__ __launch_bounds__(256) void relk_cvt(const float* __restrict__ RELF,
                                                u16* __restrict__ REL) {
  int i = blockIdx.x * 256 + threadIdx.x;
  if (i < POS * HID) REL[i] = f2b(RELF[i]);
}

// ---------------------------------------------------------------- GEMM
// ROUND-4 VERIFIED KERNEL (204 us QKV, MfmaUtil 47, 0 conflicts, VGPR 108).
// 256x256 tile, BK=32, ring-4 LDS, register-pipelined, ONE barrier per tile.
//
// Per tile t (regs entering: afC/bfC = ph0 frags of tile t, read last tile):
//   glds A(t+3); ds_read af1 (ph1 A-frags, buffer t);
//   lgkmcnt(4) [drains prev H-reads]; 16 MFMA ph0;
//   glds B(t+3); lgkmcnt(0) [af1 done -> all reads of buffer t done];
//   vmcnt(8) [buffer t+1 staged]; s_barrier;
//   ds_read afN/bfN (ph0 frags of t+1, buffer t+1);   // overlaps ph1 MFMA
//   16 MFMA ph1; rotate afC<-afN, bfC<-bfN.
//
// Hazard ledger:
//  - vmcnt: 4 loads/thread/tile; 8 issued after buffer t+1's stage ->
//    vmcnt(8)+barrier guarantees t+1 staged for ALL waves. Tail vmcnt(4)/(0).
//  - WAR: stage into buffer (t+4)&3 == t issued after barrier of tile t;
//    all reads of buffer t complete before that barrier (H via data-dep wait
//    before ph0 MFMA; af1 via explicit lgkmcnt(0) BEFORE the barrier).
//
// LDS layout (0-conflict, verified r3/r4): logical [256 r][32 k] -> physical
// [128 prow][8 slot]: prow=r>>1, sl=(r&1)*4+(k>>3), phys p = sl ^ (prow&7).
// Stage keeps LDS dest LINEAR and applies the same involution to the GLOBAL
// source address (both-sides-or-neither).
#define BMT 256
#define BNT 256
#define BKT 32
#define NT  (HID / BKT)   // 64

__global__ __launch_bounds__(512, 2) void gemm_bt(const u16* __restrict__ A,
                                                  const u16* __restrict__ Bt,
                                                  u16* __restrict__ Co,
                                                  float* __restrict__ Cf,
                                                  const float* __restrict__ colscale,
                                                  int NN, int csLimit) {
  __shared__ u16 lds[4][2][BMT * BKT];  // 4 ring bufs x {A,B} x 16 KB = 128 KB
  const int tid = threadIdx.x;
  const int lane = tid & 63, w = tid >> 6;
  const int quad = lane >> 4, l = lane & 15;
  const int wm = (w >> 2) * 128, wn = (w & 3) * 64;

  // XCD mapping: per XCD a 4m x nwgy n panel -> A L2-resident, B via L3.
  const int orig = blockIdx.y * gridDim.x + blockIdx.x;
  const int xcd = orig & 7, k = orig >> 3;
  const int bm = (xcd * 4 + (k & 3)) * BMT;
  const int bn = (k >> 2) * BNT;

  // Read-side swizzle constant (see layout comment).
  const int rdoff = (l >> 1) * 64 + (((((l & 1) << 2) | quad)) ^ ((l >> 1) & 7)) * 8;

  // Stage side: lane writes phys slot lane&7 at prow base+lane>>3; fetch the
  // logical chunk sl = (lane&7)^(lane>>3): global row 2*(lane>>3)+(sl>>2),
  // k-chunk sl&3.
  const int sl = (lane & 7) ^ (lane >> 3);
  const int srow = ((lane >> 3) << 1) + (sl >> 2);
  const int sk = (sl & 3) * 8;
  const u16* Ag0 = A + (size_t)(bm + w * 32 + srow) * HID + sk;
  const u16* Ag1 = Ag0 + (size_t)16 * HID;
  const u16* Bg0 = Bt + (size_t)(bn + w * 32 + srow) * HID + sk;
  const u16* Bg1 = Bg0 + (size_t)16 * HID;

  f32x4 acc[8][4] = {};

  // prologue: stage tiles 0..2 (12 loads)
#pragma unroll
  for (int pt = 0; pt < 3; ++pt) {
    u16* sA = &lds[pt][0][w * 1024];
    u16* sB = &lds[pt][1][w * 1024];
    glds16(Ag0 + pt * BKT, sA);
    glds16(Ag1 + pt * BKT, sA + 512);
    glds16(Bg0 + pt * BKT, sB);
    glds16(Bg1 + pt * BKT, sB + 512);
  }
  asm volatile("s_waitcnt vmcnt(8)" ::: "memory");  // tile 0 staged
  __builtin_amdgcn_s_barrier();

  // pre-read ph0 fragments of tile 0
  bf16x8 afC[4], bfC[4], afN[4], bfN[4];
#pragma unroll
  for (int i = 0; i < 4; ++i)
    afC[i] = *(const bf16x8*)(&lds[0][0][0] + (wm + i * 16) * 32 + rdoff);
#pragma unroll
  for (int j = 0; j < 4; ++j)
    bfC[j] = *(const bf16x8*)(&lds[0][1][0] + (wn + j * 16) * 32 + rdoff);

#pragma unroll 1
  for (int t = 0; t < NT; ++t) {
    const u16* bufA = &lds[t & 3][0][0];
    u16* stA = &lds[(t + 3) & 3][0][w * 1024];
    u16* stB = &lds[(t + 3) & 3][1][w * 1024];
    const int kt = (t + 3) * BKT;
    const bool doStage = (t < NT - 3);

    // ---- ph0: stage-issue A, prefetch ph1 frags, MFMA m-half 0 ----
    if (doStage) {
      glds16(Ag0 + kt, stA);
      glds16(Ag1 + kt, stA + 512);
    }
    bf16x8 af1[4];
#pragma unroll
    for (int i = 0; i < 4; ++i)
      af1[i] = *(const bf16x8*)(bufA + (wm + 64 + i * 16) * 32 + rdoff);
    asm volatile("s_waitcnt lgkmcnt(4)" ::: "memory");  // prev H-reads done
    __builtin_amdgcn_sched_barrier(0);
    __builtin_amdgcn_s_setprio(1);
#pragma unroll
    for (int i = 0; i < 4; ++i)
#pragma unroll
      for (int j = 0; j < 4; ++j)
        acc[i][j] = MFMA16(afC[i], bfC[j], acc[i][j], 0, 0, 0);
    __builtin_amdgcn_s_setprio(0);

    // ---- ph1: stage-issue B, sync, prefetch next-tile ph0 frags, MFMA ----
    if (doStage) {
      glds16(Bg0 + kt, stB);
      glds16(Bg1 + kt, stB + 512);
    }
    asm volatile("s_waitcnt lgkmcnt(0)" ::: "memory");  // af1 done (WAR-critical)
    if (t < NT - 3)       asm volatile("s_waitcnt vmcnt(8)" ::: "memory");
    else if (t == NT - 3) asm volatile("s_waitcnt vmcnt(4)" ::: "memory");
    else if (t == NT - 2) asm volatile("s_waitcnt vmcnt(0)" ::: "memory");
    __builtin_amdgcn_sched_barrier(0);
    if (t < NT - 1) {
      __builtin_amdgcn_s_barrier();
      const u16* nA = &lds[(t + 1) & 3][0][0];
      const u16* nB = &lds[(t + 1) & 3][1][0];
#pragma unroll
      for (int i = 0; i < 4; ++i)
        afN[i] = *(const bf16x8*)(nA + (wm + i * 16) * 32 + rdoff);
#pragma unroll
      for (int j = 0; j < 4; ++j)
        bfN[j] = *(const bf16x8*)(nB + (wn + j * 16) * 32 + rdoff);
    }
    __builtin_amdgcn_s_setprio(1);
#pragma unroll
    for (int i = 0; i < 4; ++i)
#pragma unroll
      for (int j = 0; j < 4; ++j)
        acc[4 + i][j] = MFMA16(af1[i], bfC[j], acc[4 + i][j], 0, 0, 0);
    __builtin_amdgcn_s_setprio(0);
#pragma unroll
    for (int r = 0; r < 4; ++r) {
      afC[r] = afN[r];
      bfC[r] = bfN[r];
    }
  }

  // epilogue
#pragma unroll
  for (int i = 0; i < 8; ++i)
#pragma unroll
    for (int j = 0; j < 4; ++j)
#pragma unroll
      for (int r = 0; r < 4; ++r) {
        int row = bm + wm + i * 16 + quad * 4 + r;
        int col = bn + wn + j * 16 + l;
        float v = acc[i][j][r];
        if (colscale && col < csLimit) v *= colscale[col & (HD - 1)];
        if (Cf) Cf[(size_t)row * NN + col] = v;
        else    Co[(size_t)row * NN + col] = f2b(v);
      }
}

// ---------------------------------------------------------------- attention
// 1 wave per (n,h). CHANGE vs r4: Q/K/rel fragments loaded DIRECTLY
// global->reg (each frag is a contiguous 16B at the lane's (row, k-chunk)
// coords) -- phase-1 LDS staging + its barrier removed (data is L2-warm;
// staging was pure latency). LDS now only vt/ps for the PV phase, with
// 64B rows + XOR slot swizzle (slot = chunk ^ ((row>>1)&3), uniform 2-way):
// 9216 B/block -> ~16 co-resident blocks/CU (was 11).
__global__ __launch_bounds__(64, 4) void attn_kernel(const u16* __restrict__ qkv,
                                                     const u16* __restrict__ relg,
                                                     u16* __restrict__ og) {
  __shared__ u16 vt[128 * 32];  // V^T rows d: 32 ctx, swizzled (8192 B)
  __shared__ u16 ps[16 * 32];   // P rows c: 32 ctx, swizzled (1024 B)
  const int n = blockIdx.x, h = blockIdx.y;
  const int lane = threadIdx.x;
  const int quad = lane >> 4, l = lane & 15;
  const int base = n * CHUNK;
  const u16x8 zero8 = {0, 0, 0, 0, 0, 0, 0, 0};

  const u16* qg = qkv + h * HD;
  const u16* kg = qkv + 2048 + h * HD;
  const u16* vg = qkv + 4096 + h * HD;

  // V prefetch into regs (written swizzled to vt after scores)
  u16x8 vld[8];
#pragma unroll
  for (int i = 0; i < 8; ++i) {
    int id = lane + 64 * i;
    int ctx = id & 31, dc = id >> 5;
    int s = base + ctx - MP;
    vld[i] = (ctx < CTX && s >= 0 && s < S_LEN)
                 ? *(const u16x8*)(vg + (size_t)s * NQKV + dc * 8)
                 : zero8;
  }

  // direct global->reg fragment loads (validity per lane):
  //   aQ:  Q row l          (valid l<CHUNK && base+l<S)
  //   bK0: K ctx row l      (s = base+l-12; valid s>=0; s<S always)
  //   bK1: K ctx row 16+l   (valid l<8 && base+4+l<S)
  const bool qv = (l < CHUNK) && (base + l < S_LEN);
  const bool k0v = (base + l - MP) >= 0;
  const bool k1v = (l < 8) && (base + 4 + l < S_LEN);
  const u16* qrow = qg + (size_t)(base + l) * NQKV;
  const u16* k0row = kg + (size_t)(base + l - MP) * NQKV;
  const u16* k1row = kg + (size_t)(base + 4 + l) * NQKV;

  bf16x8 aQf[4], bK0f[4], bK1f[4];
#pragma unroll
  for (int t = 0; t < 4; ++t) {
    int d0 = t * 32 + quad * 8;
    aQf[t] = qv ? *(const bf16x8*)(qrow + d0) : (bf16x8)zero8;
    bK0f[t] = k0v ? *(const bf16x8*)(k0row + d0) : (bf16x8)zero8;
    bK1f[t] = k1v ? *(const bf16x8*)(k1row + d0) : (bf16x8)zero8;
  }

  // scores: ac0 (ctx 0..15), ac1 (ctx 16..31), bd (pos 0..15)
  f32x4 ac0 = {0, 0, 0, 0}, ac1 = {0, 0, 0, 0}, bd = {0, 0, 0, 0};
#pragma unroll
  for (int t = 0; t < 4; ++t) {
    int d0 = t * 32;
    bf16x8 bR = (bf16x8)zero8;
    if (l < POS)
      bR = *(const bf16x8*)(relg + (size_t)l * HID + h * HD + d0 + quad * 8);
    ac0 = MFMA16(aQf[t], bK0f[t], ac0, 0, 0, 0);
    ac1 = MFMA16(aQf[t], bK1f[t], ac1, 0, 0, 0);
    bd = MFMA16(aQf[t], bR, bd, 0, 0, 0);
  }

  // softcap + softmax (C/D layout: row c = quad*4+r, col ctx = l / 16+l)
  float p0[4], p1[4];
#pragma unroll
  for (int r = 0; r < 4; ++r) {
    int c = quad * 4 + r;
    int pi0 = l - c;
    int pi1 = 16 + l - c;
    int sp0 = pi0 < 0 ? 0 : (pi0 > 15 ? 15 : pi0);
    int sp1 = pi1 < 0 ? 0 : (pi1 > 15 ? 15 : pi1);
    float b0 = __shfl(bd[r], quad * 16 + sp0, 64);
    float b1 = __shfl(bd[r], quad * 16 + sp1, 64);
    b0 = (pi0 >= 0 && pi0 < POS) ? b0 : 0.0f;
    b1 = (pi1 >= 0 && pi1 < POS) ? b1 : 0.0f;
    float s0 = tanhf((ac0[r] + b0) * (1.0f / 50.0f)) * 50.0f;
    float s1 = tanhf((ac1[r] + b1) * (1.0f / 50.0f)) * 50.0f;
    bool v1 = (l < (CTX - 16));
    if (!v1) s1 = -1e30f;
    float mx = fmaxf(s0, s1);
#pragma unroll
    for (int d = 1; d < 16; d <<= 1) mx = fmaxf(mx, __shfl_xor(mx, d, 64));
    float e0 = __expf(s0 - mx);
    float e1 = v1 ? __expf(s1 - mx) : 0.0f;
    float sm = e0 + e1;
#pragma unroll
    for (int d = 1; d < 16; d <<= 1) sm += __shfl_xor(sm, d, 64);
    float inv = 1.0f / sm;
    p0[r] = e0 * inv;
    p1[r] = e1 * inv;
  }

  // phase2: swizzled writes. slot(row, chunk) = chunk ^ ((row>>1)&3).
#pragma unroll
  for (int i = 0; i < 8; ++i) {
    int id = lane + 64 * i;
    int ctx = id & 31, dc = id >> 5;
#pragma unroll
    for (int jj = 0; jj < 8; ++jj) {
      int d = dc * 8 + jj;
      int fq = (d >> 1) & 3;
      vt[d * 32 + (((ctx >> 3) ^ fq) << 3) + (ctx & 7)] = vld[i][jj];
    }
  }
#pragma unroll
  for (int r = 0; r < 4; ++r) {
    int c = quad * 4 + r;
    int fc = (c >> 1) & 3;
    ps[c * 32 + (((l >> 3) ^ fc) << 3) + (l & 7)] = f2b(p0[r]);
    ps[c * 32 + ((((16 + l) >> 3) ^ fc) << 3) + (l & 7)] = f2b(p1[r]);
  }
  __syncthreads();

  // PV: out[c][d] = sum_ctx P[c][ctx] * V[ctx][d]
  const int fl = (l >> 1) & 3;  // (row>>1)&3 for rows l and nt*16+l alike
  bf16x8 aP = *(const bf16x8*)(ps + l * 32 + ((quad ^ fl) << 3));
#pragma unroll
  for (int nt = 0; nt < 8; ++nt) {
    int d = nt * 16 + l;
    bf16x8 bV = *(const bf16x8*)(vt + d * 32 + ((quad ^ fl) << 3));
    f32x4 o = {0, 0, 0, 0};
    o = MFMA16(aP, bV, o, 0, 0, 0);
#pragma unroll
    for (int r = 0; r < 4; ++r) {
      int c = quad * 4 + r;
      int s = base + c;
      if (c < CHUNK && s < S_LEN)
        og[(size_t)s * HID + h * HD + nt * 16 + l] = f2b(o[r]);
    }
  }
}

// ---------------------------------------------------------------- launch
extern "C" void kernel_launch(void* const* d_in, const int* in_sizes, int n_in,
                              void* d_out, int out_size, void* d_ws, size_t ws_size,
                              hipStream_t stream) {
  const float* x = (const float*)d_in[0];
  const float* pos = (const float*)d_in[1];
  const float* Wq = (const float*)d_in[2];
  const float* Wk = (const float*)d_in[3];
  const float* Wv = (const float*)d_in[4];
  const float* Wrel = (const float*)d_in[5];
  const float* Wpost = (const float*)d_in[6];
  const float* pds = (const float*)d_in[7];

  char* ws = (char*)d_ws;
  u16* WT  = (u16*)(ws);                      // 4 x [2048][2048] bf16 = 32 MB
  u16* xb  = (u16*)(ws + 33554432);           // [8192][2048] bf16 = 32 MB
  u16* AO  = xb;                              // alias: xb dead after QKV GEMM
  u16* QKV = (u16*)(ws + 67108864);           // [8192][6144] bf16 = 96 MB
  float* RELF = (float*)(ws + 167772160);     // [13][2048] f32
  u16* REL = (u16*)(ws + 167878656);          // [13][2048] bf16
  float* QS = (float*)(ws + 167931904);       // [128] f32

  const int NX = S_LEN * HID;
  f32_to_bf16<<<NX / 4 / 256, 256, 0, stream>>>(x, xb, NX);

  transpose4<<<dim3(32, 32, 4), 256, 0, stream>>>(Wq, Wk, Wv, Wpost, WT);
  qscale_kernel<<<1, 128, 0, stream>>>(pds, QS);

  hipMemsetAsync(RELF, 0, POS * HID * sizeof(float), stream);
  relk_atomic<<<dim3(8, 8), 256, 0, stream>>>(pos, Wrel, RELF);
  relk_cvt<<<(POS * HID + 255) / 256, 256, 0, stream>>>(RELF, REL);

  // fused QKV GEMM: Bt rows 0..6143 of WT; colscale on Q columns only
  gemm_bt<<<dim3(32, 24), 512, 0, stream>>>(xb, WT, QKV, nullptr, QS, NQKV, 2048);

  attn_kernel<<<dim3(NBLK, NH), 64, 0, stream>>>(QKV, REL, AO);

  // post GEMM: Bt = transposed Wpost (slab 3), f32 out
  gemm_bt<<<dim3(32, 8), 512, 0, stream>>>(AO, WT + (size_t)3 * HID * HID,
                                           nullptr, (float*)d_out, nullptr, HID, 0);
}